// Round 2
// baseline (264.072 us; speedup 1.0000x reference)
//
#include <hip/hip_runtime.h>

#define BB  8
#define CC  64
#define HH  128
#define WW  128
#define OCC 18   // 2*KK offset channels
#define XP  133  // padded spatial dim (pad 2 low, 3 high; offsets clipped to +-1)
#define SP  72   // LDS pitch in shorts (144B: 16B-aligned, measured 0 conflicts)
#define XTP 68   // transpose-LDS pitch (prep)

typedef __attribute__((ext_vector_type(8)))  short bf16x8;
typedef __attribute__((ext_vector_type(16))) float f32x16;

static __device__ __forceinline__ ushort f2bf(float f) {
    union { float f; unsigned u; } v; v.f = f;
    unsigned r = (v.u + 0x7FFFu + ((v.u >> 16) & 1u)) >> 16;  // RNE
    return (ushort)r;
}

// ---------------------------------------------------------------------------
// PREP (unchanged): blocks 0..2047 build XT with batch-per-XCD placement
// (b = blockIdx&7 so XT[b] is written by—and stays resident in—XCD b's L2);
// blocks 2048..2247 build WAf; 2248..2391 build WDf.
// WAf: [t 25][cs 4][lane 64][8]  lane l: oc=l&31, c=cs*16+(l>>5)*8+j
// WDf: [t 9][mt 2][cs 4][lane 64][8] lane l: o=mt*32+(l&31), same c map
// ---------------------------------------------------------------------------
__global__ __launch_bounds__(256) void prep_kernel(
    const float* __restrict__ x, const float* __restrict__ w,
    const float* __restrict__ ow, ushort* __restrict__ XT,
    ushort* __restrict__ WAf, ushort* __restrict__ WDf)
{
    __shared__ ushort T[64 * XTP];
    const int tid = threadIdx.x;
    const int phys = blockIdx.x;

    if (phys >= 2 * BB * HH) {                    // weight-prep blocks
        int id = phys - 2 * BB * HH;
        if (id < 200) {                           // WAf: 51200 elements
            int idx = id * 256 + tid;
            int j  = idx & 7;
            int l  = (idx >> 3) & 63;
            int cs = (idx >> 9) & 3;
            int t  = idx >> 11;
            int oc = l & 31;
            int c  = cs * 16 + (l >> 5) * 8 + j;
            float v = (oc < OCC) ? ow[((size_t)(oc * CC + c)) * 25 + t] : 0.f;
            WAf[idx] = f2bf(v);
        } else {                                  // WDf: 36864 elements
            int idx = (id - 200) * 256 + tid;
            int j  = idx & 7;
            int l  = (idx >> 3) & 63;
            int cs = (idx >> 9) & 3;
            int mt = (idx >> 11) & 1;
            int t  = idx >> 12;
            int o  = mt * 32 + (l & 31);
            int c  = cs * 16 + (l >> 5) * 8 + j;
            WDf[idx] = f2bf(w[((size_t)(o * CC + c)) * 9 + t]);
        }
        return;
    }

    // ---- XT blocks: batch-per-XCD swizzle
    const int b    = phys & 7;                    // XCD id == batch
    const int idx  = phys >> 3;                   // 0..255 within batch
    const int half = idx & 1;
    const int y    = idx >> 1;

    // y-border zero rows {0,1,130,131,132}: 5*XP*8 uint4s spread over the
    // first 21 blocks of this batch (kept on the owning XCD)
    {
        int j = idx * 256 + tid;
        if (j < 5 * XP * 8) {
            int r   = j / (XP * 8);
            int off = j % (XP * 8);
            int yp  = (r < 2) ? r : (128 + r);
            ((uint4*)(XT + ((size_t)b * XP + yp) * XP * 64))[off] = make_uint4(0, 0, 0, 0);
        }
    }

    const int p   = tid & 63;
    const int ch4 = tid >> 6;
    const float* xb = x + (size_t)b * CC * HH * WW + (size_t)y * WW + half * 64;
#pragma unroll
    for (int i = 0; i < 16; i++) {
        int c = i * 4 + ch4;
        T[p * XTP + c] = f2bf(xb[(size_t)c * HH * WW + p]);
    }
    __syncthreads();

    ushort* orow = XT + (((size_t)b * XP + (y + 2)) * XP) * 64;

    if (half == 0) {                              // x' in {0,1}: zeros
        if (tid < 16) {
            int col = tid >> 3;
            ((uint4*)(orow + (size_t)col * 64))[tid & 7] = make_uint4(0, 0, 0, 0);
        }
    } else {                                      // x' in {130,131,132}: zeros
        if (tid < 24) {
            int col = 130 + (tid >> 3);
            ((uint4*)(orow + (size_t)col * 64))[tid & 7] = make_uint4(0, 0, 0, 0);
        }
    }

#pragma unroll
    for (int g = 0; g < 2; g++) {                 // interior: x' = half*64+pl+2
        int i2 = g * 256 + tid;
        int pl = i2 >> 3;
        int part = i2 & 7;
        uint2 lo = *(const uint2*)&T[pl * XTP + part * 8];
        uint2 hi = *(const uint2*)&T[pl * XTP + part * 8 + 4];
        uint4 wv; wv.x = lo.x; wv.y = lo.y; wv.z = hi.x; wv.w = hi.y;
        ((uint4*)(orow + ((size_t)(half * 64 + pl + 2)) * 64))[part] = wv;
    }
}

// ---------------------------------------------------------------------------
// Phase-B helpers: load one corner's 4 B-fragments; run one corner's 8 MFMA
// (2 o-tiles x 4 cs, partials start from hoisted zero) + f32 weight-combine.
// ---------------------------------------------------------------------------
static __device__ __forceinline__ void loadq(bf16x8* q, const ushort* cp) {
    q[0] = *(const bf16x8*)(cp);
    q[1] = *(const bf16x8*)(cp + 16);
    q[2] = *(const bf16x8*)(cp + 32);
    q[3] = *(const bf16x8*)(cp + 48);
}

static __device__ __forceinline__ void corner_mma(
    const bf16x8* q, float wgt, const bf16x8* a0, const bf16x8* a1,
    const f32x16& kZero, f32x16& acc0, f32x16& acc1)
{
    f32x16 p0 = __builtin_amdgcn_mfma_f32_32x32x16_bf16(a0[0], q[0], kZero, 0, 0, 0);
    f32x16 p1 = __builtin_amdgcn_mfma_f32_32x32x16_bf16(a1[0], q[0], kZero, 0, 0, 0);
    p0 = __builtin_amdgcn_mfma_f32_32x32x16_bf16(a0[1], q[1], p0, 0, 0, 0);
    p1 = __builtin_amdgcn_mfma_f32_32x32x16_bf16(a1[1], q[1], p1, 0, 0, 0);
    p0 = __builtin_amdgcn_mfma_f32_32x32x16_bf16(a0[2], q[2], p0, 0, 0, 0);
    p1 = __builtin_amdgcn_mfma_f32_32x32x16_bf16(a1[2], q[2], p1, 0, 0, 0);
    p0 = __builtin_amdgcn_mfma_f32_32x32x16_bf16(a0[3], q[3], p0, 0, 0, 0);
    p1 = __builtin_amdgcn_mfma_f32_32x32x16_bf16(a1[3], q[3], p1, 0, 0, 0);
#pragma unroll
    for (int r = 0; r < 16; r++) {
        acc0[r] += wgt * p0[r];
        acc1[r] += wgt * p1[r];
    }
}

// ---------------------------------------------------------------------------
// FUSED kernel, round 10: half-row blocks (grid 2048, 128 threads = 2 waves).
// Wave = 32 px x 64 o. Phase A: offset conv for own px tile (all 4 cs,
// wave-private off_lds, no A->B barrier). Phase B: corner-MFMA from L2-hot XT
// with an explicit 2-deep corner pipeline (loads stay >=1 corner ahead).
// ---------------------------------------------------------------------------
__global__ __launch_bounds__(128, 3) void fused_kernel(
    const ushort* __restrict__ XT, const ushort* __restrict__ WAf,
    const ushort* __restrict__ WDf, const float* __restrict__ ob,
    float* __restrict__ out)
{
    __shared__ __align__(16) ushort XROW[68 * SP];   // 9792 B
    __shared__ float off_lds[OCC * 64];              // 4608 B

    const int tid  = threadIdx.x;
    const int lane = tid & 63;
    const int n    = lane & 31;
    const int h    = lane >> 5;
    const int wv   = tid >> 6;        // wave id = px tile (0/1)
    const int pxl  = wv * 32 + n;     // local pixel 0..63

    // batch-per-XCD swizzle: same mapping as prep => XT[b] is L2-resident here
    const int b    = blockIdx.x & 7;
    const int idx  = blockIdx.x >> 3;
    const int half = idx & 1;
    const int y    = idx >> 1;

    // ================= Phase A: offset conv (half row) ====================
    {
        f32x16 acc = {};
        const ushort* src0 = XT + (((size_t)b * XP + y) * XP + half * 64) * 64;

        for (int ky = 0; ky < 5; ky++) {
            if (ky) __syncthreads();              // prior ds_reads done
            const ushort* src = src0 + (size_t)ky * XP * 64;
            for (int i = tid; i < 68 * 8; i += 128) {
                int pl = i >> 3, ch = (i & 7) * 8;
                *(uint4*)&XROW[pl * SP + ch] = *(const uint4*)(src + (size_t)pl * 64 + ch);
            }
            __syncthreads();

#pragma unroll
            for (int kx = 0; kx < 5; kx++) {
                const int t = ky * 5 + kx;
                const ushort* bbase = &XROW[(pxl + kx) * SP + h * 8];
#pragma unroll
                for (int cs = 0; cs < 4; cs++) {
                    bf16x8 af = *(const bf16x8*)(WAf + (((size_t)t * 4 + cs) * 64 + lane) * 8);
                    bf16x8 bf = *(const bf16x8*)(bbase + cs * 16);
                    acc = __builtin_amdgcn_mfma_f32_32x32x16_bf16(af, bf, acc, 0, 0, 0);
                }
            }
        }

        // off_lds write: C/D col=lane&31 (px), row=(r&3)+8*(r>>2)+4*h (oc).
        // Each wave produces ALL oc for ITS px tile -> wave-private, no barrier.
#pragma unroll
        for (int r = 0; r < 16; r++) {
            int oc = (r & 3) + 8 * (r >> 2) + 4 * h;
            if (oc < OCC) {
                float v = acc[r] + ob[oc];
                off_lds[oc * 64 + pxl] = fminf(fmaxf(v, -1.f), 1.f);
            }
        }
    }
    // NOTE: no __syncthreads — Phase B reads only this wave's own off_lds
    // columns, and XROW is dead (no further writes to it).

    // ================= Phase B: corner-MFMA deform conv ===================
    f32x16 acc0 = {}, acc1 = {};      // o-tiles 0 / 1
    f32x16 kZero = {};
    const ushort* xtb = XT + (size_t)b * XP * XP * 64 + h * 8;  // fold h-offset
    const int pxg = half * 64 + pxl;  // global x of this lane's pixel

    for (int t = 0; t < 9; t++) {
        float dy = off_lds[(2 * t) * 64 + pxl];
        float dx = off_lds[(2 * t + 1) * 64 + pxl];
        float py  = (float)(y + t / 3 - 1) + dy;
        float pxf = (float)(pxg + t % 3 - 1) + dx;
        float y0f = floorf(py), x0f = floorf(pxf);
        float fy = py - y0f, fx = pxf - x0f;
        int iy = (int)y0f + 2, ix = (int)x0f + 2;          // padded coords
        float w00 = (1.f - fy) * (1.f - fx), w01 = (1.f - fy) * fx;
        float w10 = fy * (1.f - fx),         w11 = fy * fx;

        bf16x8 a0[4], a1[4];
#pragma unroll
        for (int cs = 0; cs < 4; cs++) {
            a0[cs] = *(const bf16x8*)(WDf + (((size_t)(t * 2 + 0) * 4 + cs) * 64 + lane) * 8);
            a1[cs] = *(const bf16x8*)(WDf + (((size_t)(t * 2 + 1) * 4 + cs) * 64 + lane) * 8);
        }

        const ushort* c00 = xtb + ((size_t)iy * XP + ix) * 64;
        const ushort* c10 = c00 + (size_t)XP * 64;

        // 2-deep corner pipeline: loads stay one full corner (8 MFMA + 32 FMA)
        // ahead of the MFMAs that consume them.
        bf16x8 qA[4], qB[4];
        loadq(qA, c00);                            // corner 00
        loadq(qB, c00 + 64);                       // corner 01
        corner_mma(qA, w00, a0, a1, kZero, acc0, acc1);
        loadq(qA, c10);                            // corner 10
        corner_mma(qB, w01, a0, a1, kZero, acc0, acc1);
        loadq(qB, c10 + 64);                       // corner 11
        corner_mma(qA, w10, a0, a1, kZero, acc0, acc1);
        corner_mma(qB, w11, a0, a1, kZero, acc0, acc1);
    }

    // epilogue: C/D col=lane&31 (px), row=(r&3)+8*(r>>2)+4*h (o)
#pragma unroll
    for (int r = 0; r < 16; r++) {
        int o = (r & 3) + 8 * (r >> 2) + 4 * h;
        float* orow = out + ((size_t)(b * CC + o) * HH + y) * WW + pxg;
        orow[0] = acc0[r];
        orow[(size_t)32 * HH * WW] = acc1[r];
    }
}

// ---------------------------------------------------------------------------
extern "C" void kernel_launch(void* const* d_in, const int* in_sizes, int n_in,
                              void* d_out, int out_size, void* d_ws, size_t ws_size,
                              hipStream_t stream)
{
    const float* x  = (const float*)d_in[0];   // (8,64,128,128)
    const float* w  = (const float*)d_in[1];   // (64,64,3,3)
    const float* ow = (const float*)d_in[2];   // (18,64,5,5)
    const float* ob = (const float*)d_in[3];   // (18,)
    float* out = (float*)d_out;                // (8,64,128,128)

    // workspace: XT 18,113,536 | WAf 102,400 | WDf 73,728
    ushort* XT  = (ushort*)d_ws;
    ushort* WAf = (ushort*)((char*)d_ws + 18113536);
    ushort* WDf = (ushort*)((char*)d_ws + 18215936);

    prep_kernel<<<2 * BB * HH + 344, 256, 0, stream>>>(x, w, ow, XT, WAf, WDf);
    fused_kernel<<<2 * BB * HH, 128, 0, stream>>>(XT, WAf, WDf, ob, out);
}

// Round 4
// 179.161 us; speedup vs baseline: 1.4739x; 1.4739x over previous
//
#include <hip/hip_runtime.h>

#define BB  8
#define CC  64
#define HH  128
#define WW  128
#define OCC 18   // 2*KK offset channels
#define XP  133  // padded spatial dim (pad 2 low, 3 high; offsets clipped to +-1)
#define SP  72   // LDS pitch in shorts (144B: 16B-aligned, measured 0 conflicts)
#define XTP 68   // transpose-LDS pitch (prep)

typedef __attribute__((ext_vector_type(8)))  short bf16x8;
typedef __attribute__((ext_vector_type(16))) float f32x16;

static __device__ __forceinline__ ushort f2bf(float f) {
    union { float f; unsigned u; } v; v.f = f;
    unsigned r = (v.u + 0x7FFFu + ((v.u >> 16) & 1u)) >> 16;  // RNE
    return (ushort)r;
}
static __device__ __forceinline__ float bfu(unsigned u) {
    union { unsigned u; float f; } v; v.u = u; return v.f;
}

// ---------------------------------------------------------------------------
// PREP (unchanged): blocks 0..2047 build XT with batch-per-XCD placement
// (b = blockIdx&7 so XT[b] is written by—and stays resident in—XCD b's L2);
// blocks 2048..2247 build WAf; 2248..2391 build WDf.
// WAf: [t 25][cs 4][lane 64][8]  lane l: oc=l&31, c=cs*16+(l>>5)*8+j
// WDf: [t 9][mt 2][cs 4][lane 64][8] lane l: o=mt*32+(l&31), same c map
// ---------------------------------------------------------------------------
__global__ __launch_bounds__(256) void prep_kernel(
    const float* __restrict__ x, const float* __restrict__ w,
    const float* __restrict__ ow, ushort* __restrict__ XT,
    ushort* __restrict__ WAf, ushort* __restrict__ WDf)
{
    __shared__ ushort T[64 * XTP];
    const int tid = threadIdx.x;
    const int phys = blockIdx.x;

    if (phys >= 2 * BB * HH) {                    // weight-prep blocks
        int id = phys - 2 * BB * HH;
        if (id < 200) {                           // WAf: 51200 elements
            int idx = id * 256 + tid;
            int j  = idx & 7;
            int l  = (idx >> 3) & 63;
            int cs = (idx >> 9) & 3;
            int t  = idx >> 11;
            int oc = l & 31;
            int c  = cs * 16 + (l >> 5) * 8 + j;
            float v = (oc < OCC) ? ow[((size_t)(oc * CC + c)) * 25 + t] : 0.f;
            WAf[idx] = f2bf(v);
        } else {                                  // WDf: 36864 elements
            int idx = (id - 200) * 256 + tid;
            int j  = idx & 7;
            int l  = (idx >> 3) & 63;
            int cs = (idx >> 9) & 3;
            int mt = (idx >> 11) & 1;
            int t  = idx >> 12;
            int o  = mt * 32 + (l & 31);
            int c  = cs * 16 + (l >> 5) * 8 + j;
            WDf[idx] = f2bf(w[((size_t)(o * CC + c)) * 9 + t]);
        }
        return;
    }

    // ---- XT blocks: batch-per-XCD swizzle
    const int b    = phys & 7;                    // XCD id == batch
    const int idx  = phys >> 3;                   // 0..255 within batch
    const int half = idx & 1;
    const int y    = idx >> 1;

    // y-border zero rows {0,1,130,131,132}: 5*XP*8 uint4s spread over the
    // first 21 blocks of this batch (kept on the owning XCD)
    {
        int j = idx * 256 + tid;
        if (j < 5 * XP * 8) {
            int r   = j / (XP * 8);
            int off = j % (XP * 8);
            int yp  = (r < 2) ? r : (128 + r);
            ((uint4*)(XT + ((size_t)b * XP + yp) * XP * 64))[off] = make_uint4(0, 0, 0, 0);
        }
    }

    const int p   = tid & 63;
    const int ch4 = tid >> 6;
    const float* xb = x + (size_t)b * CC * HH * WW + (size_t)y * WW + half * 64;
#pragma unroll
    for (int i = 0; i < 16; i++) {
        int c = i * 4 + ch4;
        T[p * XTP + c] = f2bf(xb[(size_t)c * HH * WW + p]);
    }
    __syncthreads();

    ushort* orow = XT + (((size_t)b * XP + (y + 2)) * XP) * 64;

    if (half == 0) {                              // x' in {0,1}: zeros
        if (tid < 16) {
            int col = tid >> 3;
            ((uint4*)(orow + (size_t)col * 64))[tid & 7] = make_uint4(0, 0, 0, 0);
        }
    } else {                                      // x' in {130,131,132}: zeros
        if (tid < 24) {
            int col = 130 + (tid >> 3);
            ((uint4*)(orow + (size_t)col * 64))[tid & 7] = make_uint4(0, 0, 0, 0);
        }
    }

#pragma unroll
    for (int g = 0; g < 2; g++) {                 // interior: x' = half*64+pl+2
        int i2 = g * 256 + tid;
        int pl = i2 >> 3;
        int part = i2 & 7;
        uint2 lo = *(const uint2*)&T[pl * XTP + part * 8];
        uint2 hi = *(const uint2*)&T[pl * XTP + part * 8 + 4];
        uint4 wv; wv.x = lo.x; wv.y = lo.y; wv.z = hi.x; wv.w = hi.y;
        ((uint4*)(orow + ((size_t)(half * 64 + pl + 2)) * 64))[part] = wv;
    }
}

// ---------------------------------------------------------------------------
// FUSED kernel, round 12: register-direct interpolation, r8-identical
// numerics (manual RNE pack — the r11 inline-asm cvt_pk was the bug).
// Geometry = r9's L2-clean full-row blocks: grid 8*128, 256 thr = 4 waves,
// wave = 32 px x 64 o. Lane (n,h) gathers the 4 corners x 4 cs x 16B for its
// OWN pixel, bilinear in f32, packs to the MFMA B register. Rolled t-loop
// (I-cache friendly), offsets re-read from LDS per tap (r8 pattern).
// No Phase-B barriers, no S-buffer LDS round-trip, 1x MFMA work.
// ---------------------------------------------------------------------------
__global__ __launch_bounds__(256, 4) void fused_kernel(
    const ushort* __restrict__ XT, const ushort* __restrict__ WAf,
    const ushort* __restrict__ WDf, const float* __restrict__ ob,
    float* __restrict__ out)
{
    __shared__ __align__(16) ushort XROW[132 * SP];   // 19008 B
    __shared__ float off_lds[OCC * 128];              // 9216 B

    const int tid  = threadIdx.x;
    const int lane = tid & 63;
    const int n    = lane & 31;
    const int h    = lane >> 5;
    const int wv   = tid >> 6;        // wave id = px tile
    const int pxl  = wv * 32 + n;     // this lane's pixel 0..127

    // batch-per-XCD swizzle: same mapping as prep => XT[b] is L2-resident here
    const int b = blockIdx.x & 7;
    const int y = blockIdx.x >> 3;

    // ================= Phase A: offset conv (full row) ====================
    {
        f32x16 acc = {};
        const ushort* src0 = XT + (((size_t)b * XP + y) * XP) * 64;

        for (int ky = 0; ky < 5; ky++) {
            if (ky) __syncthreads();              // prior ds_reads done
            const ushort* src = src0 + (size_t)ky * XP * 64;
            for (int i = tid; i < 132 * 8; i += 256) {
                int pl = i >> 3, ch = (i & 7) * 8;
                *(uint4*)&XROW[pl * SP + ch] = *(const uint4*)(src + (size_t)pl * 64 + ch);
            }
            __syncthreads();

#pragma unroll
            for (int kx = 0; kx < 5; kx++) {
                const int t = ky * 5 + kx;
                const ushort* bbase = &XROW[(pxl + kx) * SP + h * 8];
#pragma unroll
                for (int cs = 0; cs < 4; cs++) {
                    bf16x8 af = *(const bf16x8*)(WAf + (((size_t)t * 4 + cs) * 64 + lane) * 8);
                    bf16x8 bf = *(const bf16x8*)(bbase + cs * 16);
                    acc = __builtin_amdgcn_mfma_f32_32x32x16_bf16(af, bf, acc, 0, 0, 0);
                }
            }
        }

        // off_lds: C/D col=lane&31 (px), row=(r&3)+8*(r>>2)+4*h (oc).
        // Wave-private columns -> no barrier needed before Phase B.
#pragma unroll
        for (int r = 0; r < 16; r++) {
            int oc = (r & 3) + 8 * (r >> 2) + 4 * h;
            if (oc < OCC) {
                float v = acc[r] + ob[oc];
                off_lds[oc * 128 + pxl] = fminf(fmaxf(v, -1.f), 1.f);
            }
        }
    }
    // NOTE: no __syncthreads — each wave reads only its own off_lds columns
    // (same-wave LDS write->read, lgkmcnt-ordered), and XROW is dead.

    // ================= Phase B: register-direct deform conv ===============
    f32x16 acc0 = {}, acc1 = {};      // o-tiles 0 / 1
    const ushort* xtb = XT + (size_t)b * XP * XP * 64 + h * 8;  // fold h-slot

    for (int t = 0; t < 9; t++) {     // rolled: ~4KB body, I-cache friendly
        float dy = off_lds[(2 * t) * 128 + pxl];
        float dx = off_lds[(2 * t + 1) * 128 + pxl];
        float py  = (float)(y + t / 3 - 1) + dy;
        float pxf = (float)(pxl + t % 3 - 1) + dx;
        float y0f = floorf(py), x0f = floorf(pxf);
        float fy = py - y0f, fx = pxf - x0f;
        int iy = (int)y0f + 2, ix = (int)x0f + 2;          // padded coords
        float w00 = (1.f - fy) * (1.f - fx), w01 = (1.f - fy) * fx;
        float w10 = fy * (1.f - fx),         w11 = fy * fx;

        const ushort* c00 = xtb + ((size_t)iy * XP + ix) * 64;

#pragma unroll
        for (int cs = 0; cs < 4; cs++) {
            const ushort* p = c00 + cs * 16;
            uint4 q00 = *(const uint4*)(p);
            uint4 q01 = *(const uint4*)(p + 64);
            uint4 q10 = *(const uint4*)(p + XP * 64);
            uint4 q11 = *(const uint4*)(p + XP * 64 + 64);

            union { unsigned u[4]; bf16x8 v; } o4;
#pragma unroll
            for (int j = 0; j < 4; j++) {
                unsigned u00 = ((const unsigned*)&q00)[j];
                unsigned u01 = ((const unsigned*)&q01)[j];
                unsigned u10 = ((const unsigned*)&q10)[j];
                unsigned u11 = ((const unsigned*)&q11)[j];
                float lo = w00 * bfu(u00 << 16) + w01 * bfu(u01 << 16)
                         + w10 * bfu(u10 << 16) + w11 * bfu(u11 << 16);
                float hi = w00 * bfu(u00 & 0xffff0000u) + w01 * bfu(u01 & 0xffff0000u)
                         + w10 * bfu(u10 & 0xffff0000u) + w11 * bfu(u11 & 0xffff0000u);
                o4.u[j] = (unsigned)f2bf(lo) | ((unsigned)f2bf(hi) << 16);
            }

            bf16x8 a0 = *(const bf16x8*)(WDf + (((size_t)(t * 2 + 0) * 4 + cs) * 64 + lane) * 8);
            bf16x8 a1 = *(const bf16x8*)(WDf + (((size_t)(t * 2 + 1) * 4 + cs) * 64 + lane) * 8);
            acc0 = __builtin_amdgcn_mfma_f32_32x32x16_bf16(a0, o4.v, acc0, 0, 0, 0);
            acc1 = __builtin_amdgcn_mfma_f32_32x32x16_bf16(a1, o4.v, acc1, 0, 0, 0);
        }
    }

    // epilogue: C/D col=lane&31 (px), row=(r&3)+8*(r>>2)+4*h (o)
#pragma unroll
    for (int r = 0; r < 16; r++) {
        int o = (r & 3) + 8 * (r >> 2) + 4 * h;
        float* orow = out + ((size_t)(b * CC + o) * HH + y) * WW + pxl;
        orow[0] = acc0[r];
        orow[(size_t)32 * HH * WW] = acc1[r];
    }
}

// ---------------------------------------------------------------------------
extern "C" void kernel_launch(void* const* d_in, const int* in_sizes, int n_in,
                              void* d_out, int out_size, void* d_ws, size_t ws_size,
                              hipStream_t stream)
{
    const float* x  = (const float*)d_in[0];   // (8,64,128,128)
    const float* w  = (const float*)d_in[1];   // (64,64,3,3)
    const float* ow = (const float*)d_in[2];   // (18,64,5,5)
    const float* ob = (const float*)d_in[3];   // (18,)
    float* out = (float*)d_out;                // (8,64,128,128)

    // workspace: XT 18,113,536 | WAf 102,400 | WDf 73,728
    ushort* XT  = (ushort*)d_ws;
    ushort* WAf = (ushort*)((char*)d_ws + 18113536);
    ushort* WDf = (ushort*)((char*)d_ws + 18215936);

    prep_kernel<<<2 * BB * HH + 344, 256, 0, stream>>>(x, w, ow, XT, WAf, WDf);
    fused_kernel<<<BB * HH, 256, 0, stream>>>(XT, WAf, WDf, ob, out);
}